// Round 12
// baseline (110.263 us; speedup 1.0000x reference)
//
#include <hip/hip_runtime.h>

// SoftDtwRkdDistance: B=32, T=96, D=128, f32 in, scalar f32 out.
// Split design:
//   K0 xn:  row squared-norms.
//   K1 csq: B-panel through LDS (slot-rotated, conflict-free); A-panel read
//           DIRECTLY from global with 1-step register prefetch (a_nxt issued
//           under current FMAs). B staging globals prefetched chunk-ahead.
//           C' = (xn_a+xn_b-2*dot)*rg2 in diag-major global layout.
//   K2 dp:  one wave per problem; 4-deep register prefetch, 2 shfls/diag,
//           compact phase-split loops (B-side skipped where provably dead).
//   K3 reduce: means + smooth-L1.
// Fallback: if ws too small for the 38 MB C buffer, run the round-3 fused kernel.

constexpr int TT = 96;
constexpr int DD = 128;
constexpr int BB = 32;
constexpr int NP = BB * BB;               // 1024
constexpr int NPAIR = BB * (BB + 1) / 2;  // 528
constexpr int NPROB = 2 * NPAIR;          // 1056
constexpr int CSZ = TT * TT;              // 9216 floats per problem
constexpr float FINF = 1e10f;
constexpr float LOG2E = 1.4426950408889634f;
constexpr float LN2 = 0.6931471805599453f;

__device__ __forceinline__ int tri_base(int a) {   // pairs with first index < a
  return a * BB - (a * (a - 1)) / 2;
}
__device__ __forceinline__ void tri_decode(int pr, int& a, int& b) {
  a = (int)((65.0f - sqrtf(4225.0f - 8.0f * (float)pr)) * 0.5f);
  while (tri_base(a + 1) <= pr) ++a;
  while (tri_base(a) > pr) --a;
  b = a + (pr - tri_base(a));
}
__device__ __forceinline__ int diag_base(int d) {
  return (d <= 95) ? ((d * (d + 1)) >> 1)
                   : 4656 + (((d - 96) * (287 - d)) >> 1);
}
// softmin in z''-domain, op order matches reference (up, left, diag)
__device__ __forceinline__ float smin2(float u, float lf, float dg) {
  float m = fmaxf(fmaxf(u, lf), dg);
  float s = __builtin_amdgcn_exp2f(u - m) + __builtin_amdgcn_exp2f(lf - m)
          + __builtin_amdgcn_exp2f(dg - m);
  return m + __builtin_amdgcn_logf(s);
}

// K0: row squared-norms xn[2][BB*TT]
__global__ void xn_kernel(const float* __restrict__ xs,
                          const float* __restrict__ xt,
                          float* __restrict__ xn) {
  int idx = blockIdx.x * 256 + threadIdx.x;
  if (idx >= 2 * BB * TT) return;
  int which = idx / (BB * TT);
  int row = idx - which * (BB * TT);
  const float* x = which ? xt : xs;
  const float4* xv = reinterpret_cast<const float4*>(x + (size_t)row * DD);
  float acc = 0.f;
#pragma unroll
  for (int k = 0; k < DD / 4; ++k) {
    float4 v = xv[k];
    acc = fmaf(v.x, v.x, acc);
    acc = fmaf(v.y, v.y, acc);
    acc = fmaf(v.z, v.z, acc);
    acc = fmaf(v.w, v.w, acc);
  }
  xn[idx] = acc;
}

// K1: C' in diag-major global layout. One 256-thread block per (pair, tensor).
// A direct-from-global with register pipeline; B via rotated LDS.
__global__ __launch_bounds__(256)
void csq_kernel(const float* __restrict__ xs,
                const float* __restrict__ xt,
                const float* __restrict__ xn,
                const float* __restrict__ gptr,
                float* __restrict__ Cd) {
  __shared__ __align__(16) float Cs[CSZ];   // B staging (3456 floats) aliases front
  __shared__ float xna[TT];
  __shared__ float xnb[TT];

  const int pr = blockIdx.x;
  int a, b;
  tri_decode(pr, a, b);
  const int w = blockIdx.y;
  const float* x = w ? xt : xs;
  const float* xnw = xn + w * (BB * TT);
  const float* xa = x + (size_t)a * TT * DD;
  const float* xb = x + (size_t)b * TT * DD;
  const int tid = threadIdx.x;

  if (tid < TT) {
    xna[tid] = xnw[a * TT + tid];
    xnb[tid] = xnw[b * TT + tid];
  }

  // B panel: [96 rows][9 float4 slots]; row t's logical k4 block at slot
  // (k4 + t/6) & 7 (slot 8 pad) -> conflict-free rotated reads.
  float4* sb = reinterpret_cast<float4*>(Cs);          // 864 float4

  // lane remap: tx/ty per r11
  const int wv = tid >> 6;
  const int lane = tid & 63;
  const int tx = (lane & 7) + (wv & 1) * 8;      // 0..15
  const int ty = (lane >> 3) + (wv >> 1) * 8;    // 0..15
  const int t0 = ty * 6, s0 = tx * 6;

  float acc[6][6];
#pragma unroll
  for (int r = 0; r < 6; ++r)
#pragma unroll
    for (int c = 0; c < 6; ++c) acc[r][c] = 0.f;

  const float4* ga = reinterpret_cast<const float4*>(xa);  // [96][32]
  const float4* gb = reinterpret_cast<const float4*>(xb);

  // staging coords for this thread (3 slices)
  int st_t[3], st_k4[3], st_slot[3];
#pragma unroll
  for (int it = 0; it < 3; ++it) {
    int idx = tid + it * 256;          // 0..767
    st_t[it] = idx >> 3;
    st_k4[it] = idx & 7;
    st_slot[it] = (st_k4[it] + (st_t[it] / 6)) & 7;
  }

  // prefetch chunk 0 B staging + first A column
  float4 pb[3];
#pragma unroll
  for (int it = 0; it < 3; ++it)
    pb[it] = gb[st_t[it] * 32 + st_k4[it]];
  float4 a_cur[6];
#pragma unroll
  for (int r = 0; r < 6; ++r) a_cur[r] = ga[(t0 + r) * 32];

  for (int ch = 0; ch < 4; ++ch) {
    __syncthreads();   // previous chunk's B reads done before overwrite
#pragma unroll
    for (int it = 0; it < 3; ++it)
      sb[st_t[it] * 9 + st_slot[it]] = pb[it];
    if (ch < 3) {      // issue next chunk's B staging loads now
#pragma unroll
      for (int it = 0; it < 3; ++it)
        pb[it] = gb[st_t[it] * 32 + (ch + 1) * 8 + st_k4[it]];
    }
    __syncthreads();
#pragma unroll
    for (int k4 = 0; k4 < 8; ++k4) {
      // issue next A column loads (consumed next k4); hide under FMAs below
      int g4n = ch * 8 + k4 + 1;
      if (g4n > 31) g4n = 31;          // harmless dummy on very last step
      float4 a_nxt[6];
#pragma unroll
      for (int r = 0; r < 6; ++r) a_nxt[r] = ga[(t0 + r) * 32 + g4n];

      float4 bv[6];
      const int sB = (k4 + tx) & 7;
#pragma unroll
      for (int c = 0; c < 6; ++c) bv[c] = sb[(s0 + c) * 9 + sB];
#pragma unroll
      for (int r = 0; r < 6; ++r)
#pragma unroll
        for (int c = 0; c < 6; ++c) {
          acc[r][c] = fmaf(a_cur[r].x, bv[c].x, acc[r][c]);
          acc[r][c] = fmaf(a_cur[r].y, bv[c].y, acc[r][c]);
          acc[r][c] = fmaf(a_cur[r].z, bv[c].z, acc[r][c]);
          acc[r][c] = fmaf(a_cur[r].w, bv[c].w, acc[r][c]);
        }
#pragma unroll
      for (int r = 0; r < 6; ++r) a_cur[r] = a_nxt[r];
    }
  }
  __syncthreads();
  const float rg2 = -LOG2E / gptr[0];
#pragma unroll
  for (int r = 0; r < 6; ++r) {
    float xr = xna[t0 + r];
#pragma unroll
    for (int c = 0; c < 6; ++c) {
      float cv = xr + xnb[s0 + c] - 2.0f * acc[r][c];   // exact ref C
      Cs[(t0 + r) * TT + (s0 + c)] = cv * rg2;          // pre-scaled, row-major
    }
  }
  __syncthreads();

  // write-out: diag-major, coalesced; wave wv handles diagonals d ≡ wv (mod 4)
  const size_t qb = (size_t)(w * NPAIR + pr) * CSZ;
  for (int d = wv; d < 2 * TT - 1; d += 4) {
    int s = d <= 95 ? 0 : d - 95;
    int len = d <= 95 ? d + 1 : 191 - d;
    int base = diag_base(d);
    if (lane < len) {
      int i = s + lane;
      Cd[qb + base + lane] = Cs[i * TT + (d - i)];
    }
    if (len > 64 && lane < len - 64) {
      int i = s + 64 + lane;
      Cd[qb + base + 64 + lane] = Cs[i * TT + (d - i)];
    }
  }
}

// K2: DP. One wave per problem q = w*528 + pr. No LDS.
// 4-deep prefetch (slot (d-1)&3), 2 shfls/diag via shadow regs,
// compact phase-split: B-side skipped where provably NEGI.
#define ST_R(d, qa, qb) do {                                             \
    float cA = qa, cB = qb;                                              \
    { int dn = (d) + 4;                                                  \
      if (dn <= 190) { int nb = diag_base(dn);                           \
        qa = cb[nb + l]; qb = cb[nb + 64 + l]; } }                       \
    float rA1 = __shfl(A1, lm1), rB1 = __shfl(B1, lm1);                  \
    float upA = l0 ? NEGI : rA1;                                         \
    float dgA = l0 ? NEGI : pA1;                                         \
    float upB = l0 ? rA1 : rB1;                                          \
    float dgB = l0 ? pA1 : pB1;                                          \
    float nA = cA + smin2(upA, A1, dgA);                                 \
    float nB = cB + smin2(upB, B1, dgB);                                 \
    A2 = A1; B2 = B1;                                                    \
    A1 = (l < (d) + 1) ? nA : NEGI;                                      \
    B1 = (64 + l < (d) + 1) ? nB : NEGI;                                 \
    pA1 = rA1; pB1 = rB1;                                                \
  } while (0)

#define ST_RN(d, qa, qb) do {  /* rising, B provably dead (d<=63) */     \
    float cA = qa;                                                       \
    { int dn = (d) + 4;                                                  \
      if (dn <= 190) { int nb = diag_base(dn);                           \
        qa = cb[nb + l]; qb = cb[nb + 64 + l]; } }                       \
    float rA1 = __shfl(A1, lm1);                                         \
    float upA = l0 ? NEGI : rA1;                                         \
    float dgA = l0 ? NEGI : pA1;                                         \
    float nA = cA + smin2(upA, A1, dgA);                                 \
    A2 = A1;                                                             \
    A1 = (l < (d) + 1) ? nA : NEGI;                                      \
    pA1 = rA1;                                                           \
  } while (0)

#define ST_F(d, qa, qb) do {                                             \
    float cA = qa, cB = qb;                                              \
    { int dn = (d) + 4;                                                  \
      if (dn <= 190) { int nb = diag_base(dn); qa = cb[nb + l];          \
        if (dn <= 128) qb = cb[nb + 64 + l]; } }                         \
    float rA1 = __shfl(A1, lp1), rB1 = __shfl(B1, lp1);                  \
    float lfA = l63 ? rB1 : rA1;                                         \
    float dgA = l63 ? pB1 : pA1;                                         \
    float nA = cA + smin2(A1, lfA, dgA);                                 \
    float nB = cB + smin2(B1, rB1, pB1);                                 \
    A1 = (l < 191 - (d)) ? nA : NEGI;                                    \
    B1 = (64 + l < 191 - (d)) ? nB : NEGI;                               \
    pA1 = rA1; pB1 = rB1;                                                \
  } while (0)

#define ST_FN(d, qa, qb) do {  /* falling, B provably dead (d>=129) */   \
    float cA = qa;                                                       \
    { int dn = (d) + 4;                                                  \
      if (dn <= 190) { int nb = diag_base(dn); qa = cb[nb + l]; } }      \
    float rA1 = __shfl(A1, lp1);                                         \
    float lfA = l63 ? NEGI : rA1;                                        \
    float dgA = l63 ? NEGI : pA1;                                        \
    float nA = cA + smin2(A1, lfA, dgA);                                 \
    A1 = (l < 191 - (d)) ? nA : NEGI;                                    \
    pA1 = rA1;                                                           \
  } while (0)

__global__ __launch_bounds__(64)
void dp_kernel(const float* __restrict__ Cd,
               const float* __restrict__ gptr,
               float* __restrict__ dtw) {
  const int q = blockIdx.x;
  const int l = threadIdx.x;
  const float gamma = gptr[0];
  const float rg2 = -LOG2E / gamma;
  const float NEGI = FINF * rg2;          // invalid cell in z''-domain
  const float* __restrict__ cb = Cd + (size_t)q * CSZ;
  const int lp1 = (l + 1) & 63, lm1 = (l + 63) & 63;
  const bool l0 = (l == 0), l63 = (l == 63);

  // prefetch queue: slot (d-1)&3; preload diagonals 1..4
  float q0A, q0B, q1A, q1B, q2A, q2B, q3A, q3B;
  {
    int b1 = diag_base(1), b2 = diag_base(2), b3 = diag_base(3), b4 = diag_base(4);
    q0A = cb[b1 + l]; q0B = cb[b1 + 64 + l];
    q1A = cb[b2 + l]; q1B = cb[b2 + 64 + l];
    q2A = cb[b3 + l]; q2B = cb[b3 + 64 + l];
    q3A = cb[b4 + l]; q3B = cb[b4 + 64 + l];
  }

  // d=0 peel: r(0,0)'' = C''(0,0)
  float A1 = l0 ? cb[0] : NEGI;
  float B1 = NEGI, A2 = NEGI, B2 = NEGI;
  float pA1 = NEGI, pB1 = NEGI;   // shadow: last iter's shfl(A1/B1)

  // rising, B dead: d = 1..60 (15 groups), peel 61,62,63
  for (int g = 0; g < 15; ++g) {
    int d = 1 + g * 4;
    ST_RN(d,     q0A, q0B);
    ST_RN(d + 1, q1A, q1B);
    ST_RN(d + 2, q2A, q2B);
    ST_RN(d + 3, q3A, q3B);
  }
  ST_RN(61, q0A, q0B);
  ST_RN(62, q1A, q1B);
  ST_RN(63, q2A, q2B);

  // rising, full: d = 64, 65..92 (7 groups), peel 93,94,95
  ST_R(64, q3A, q3B);
  for (int g = 0; g < 7; ++g) {
    int d = 65 + g * 4;
    ST_R(d,     q0A, q0B);
    ST_R(d + 1, q1A, q1B);
    ST_R(d + 2, q2A, q2B);
    ST_R(d + 3, q3A, q3B);
  }
  ST_R(93, q0A, q0B);
  ST_R(94, q1A, q1B);
  ST_R(95, q2A, q2B);

  // d = 96 boundary: offsets (0, +1, 0); consumes q3, prefetches 100
  {
    float cA = q3A, cB = q3B;
    int nb = diag_base(100);
    q3A = cb[nb + l]; q3B = cb[nb + 64 + l];
    float rA1 = __shfl(A1, lp1), rB1 = __shfl(B1, lp1);
    float lfA = l63 ? rB1 : rA1;
    float lfB = rB1;
    float nA = cA + smin2(A1, lfA, A2);
    float nB = cB + smin2(B1, lfB, B2);
    A1 = (l < 95) ? nA : NEGI;          // len = 95
    B1 = (64 + l < 95) ? nB : NEGI;
    pA1 = rA1; pB1 = rB1;
  }

  // falling, full: d = 97..128 (8 groups)
  for (int g = 0; g < 8; ++g) {
    int d = 97 + g * 4;
    ST_F(d,     q0A, q0B);
    ST_F(d + 1, q1A, q1B);
    ST_F(d + 2, q2A, q2B);
    ST_F(d + 3, q3A, q3B);
  }
  // falling, B dead: d = 129..188 (15 groups), peel 189,190
  for (int g = 0; g < 15; ++g) {
    int d = 129 + g * 4;
    ST_FN(d,     q0A, q0B);
    ST_FN(d + 1, q1A, q1B);
    ST_FN(d + 2, q2A, q2B);
    ST_FN(d + 3, q3A, q3B);
  }
  ST_FN(189, q0A, q0B);
  ST_FN(190, q1A, q1B);

  // cell (95,95) = position 0 of diag 190 -> lane 0, A1
  if (l0) {
    int w = q >= NPAIR ? 1 : 0;
    int pr = q - w * NPAIR;
    int a, b;
    tri_decode(pr, a, b);
    float v = A1 * (-gamma * LN2);       // back to r-domain
    dtw[w * NP + a * BB + b] = v;
    dtw[w * NP + b * BB + a] = v;
  }
}

// ---------------- Fallback fused kernel (round-3, proven) ----------------
__global__ __launch_bounds__(256)
void sdtw_fused_kernel(const float* __restrict__ xs,
                       const float* __restrict__ xt,
                       const float* __restrict__ xn,
                       const float* __restrict__ gptr,
                       float* __restrict__ dtw) {
  __shared__ __align__(16) float Cs[TT * TT];
  __shared__ float xna[TT];
  __shared__ float xnb[TT];

  const int pr = blockIdx.x;
  int a, b;
  tri_decode(pr, a, b);
  const int w = blockIdx.y;
  const float* x = w ? xt : xs;
  const float* xnw = xn + w * (BB * TT);
  const float* xa = x + (size_t)a * TT * DD;
  const float* xb = x + (size_t)b * TT * DD;
  const int tid = threadIdx.x;

  if (tid < TT) {
    xna[tid] = xnw[a * TT + tid];
    xnb[tid] = xnw[b * TT + tid];
  }
  constexpr int SROW = 36;
  float* xa_s = Cs;
  float* xb_s = Cs + TT * SROW;
  const int wv = tid >> 6;
  const int lane = tid & 63;
  const int tx = (lane & 7) + (wv & 1) * 8;
  const int ty = (lane >> 3) + (wv >> 1) * 8;
  const int t0 = ty * 6, s0 = tx * 6;
  float acc[6][6];
#pragma unroll
  for (int r = 0; r < 6; ++r)
#pragma unroll
    for (int c = 0; c < 6; ++c) acc[r][c] = 0.f;
  for (int d0 = 0; d0 < DD; d0 += 32) {
    __syncthreads();
    const float4* ga = reinterpret_cast<const float4*>(xa + d0);
    const float4* gb = reinterpret_cast<const float4*>(xb + d0);
    float4* sa = reinterpret_cast<float4*>(xa_s);
    float4* sb = reinterpret_cast<float4*>(xb_s);
#pragma unroll
    for (int it = 0; it < 3; ++it) {
      int idx = tid + it * 256;
      int t = idx >> 3, k4 = idx & 7;
      sa[t * (SROW / 4) + k4] = ga[t * (DD / 4) + k4];
      sb[t * (SROW / 4) + k4] = gb[t * (DD / 4) + k4];
    }
    __syncthreads();
#pragma unroll
    for (int k4 = 0; k4 < 8; ++k4) {
      float4 av4[6], bv4[6];
#pragma unroll
      for (int r = 0; r < 6; ++r)
        av4[r] = reinterpret_cast<const float4*>(xa_s + (t0 + r) * SROW)[k4];
#pragma unroll
      for (int c = 0; c < 6; ++c)
        bv4[c] = reinterpret_cast<const float4*>(xb_s + (s0 + c) * SROW)[k4];
#pragma unroll
      for (int r = 0; r < 6; ++r)
#pragma unroll
        for (int c = 0; c < 6; ++c) {
          acc[r][c] = fmaf(av4[r].x, bv4[c].x, acc[r][c]);
          acc[r][c] = fmaf(av4[r].y, bv4[c].y, acc[r][c]);
          acc[r][c] = fmaf(av4[r].z, bv4[c].z, acc[r][c]);
          acc[r][c] = fmaf(av4[r].w, bv4[c].w, acc[r][c]);
        }
    }
  }
  __syncthreads();
#pragma unroll
  for (int r = 0; r < 6; ++r) {
    float xr = xna[t0 + r];
#pragma unroll
    for (int c = 0; c < 6; ++c)
      Cs[(t0 + r) * TT + (s0 + c)] = xr + xnb[s0 + c] - 2.0f * acc[r][c];
  }
  __syncthreads();
  if (tid >= 64) return;

  const float gamma = gptr[0];
  const float rg = -1.0f / gamma;
  const int lm1 = (lane + 63) & 63;
  float A1 = FINF, B1 = FINF, A2 = FINF, B2 = FINF;
  for (int d = 0; d < 2 * TT - 1; ++d) {
    int jA = d - lane;
    bool vA = (jA >= 0) && (jA < TT);
    float cA = Cs[vA ? lane * TT + jA : 0];
    int iB = 64 + lane;
    int jB = d - iB;
    bool vB = (lane < 32) && (jB >= 0) && (jB < TT);
    float cB = Cs[vB ? iB * TT + jB : 0];
    float rA1 = __shfl(A1, lm1);
    float rB1 = __shfl(B1, lm1);
    float rA2 = __shfl(A2, lm1);
    float rB2 = __shfl(B2, lm1);
    const bool l0 = (lane == 0);
    float upA = l0 ? FINF : rA1;
    float dgA = l0 ? FINF : rA2;
    float upB = l0 ? rA1 : rB1;
    float dgB = l0 ? rA2 : rB2;
    float z0 = upA * rg, z1 = A1 * rg, z2 = dgA * rg;
    float m = fmaxf(fmaxf(z0, z1), z2);
    float s = expf(z0 - m) + expf(z1 - m) + expf(z2 - m);
    float sminA = -gamma * (m + logf(s));
    if (d == 0) sminA = 0.f;
    float y0 = upB * rg, y1 = B1 * rg, y2 = dgB * rg;
    float mb = fmaxf(fmaxf(y0, y1), y2);
    float sb2 = expf(y0 - mb) + expf(y1 - mb) + expf(y2 - mb);
    float sminB = -gamma * (mb + logf(sb2));
    float nA = vA ? cA + sminA : FINF;
    float nB = vB ? cB + sminB : FINF;
    A2 = A1; B2 = B1; A1 = nA; B1 = nB;
  }
  if (lane == 31) {
    float v = B1;
    dtw[w * NP + a * BB + b] = v;
    dtw[w * NP + b * BB + a] = v;
  }
}

// K3: means + normalized smooth-L1 (single block).
__global__ void reduce_kernel(const float* __restrict__ dtw,
                              float* __restrict__ out) {
  __shared__ double sh[256];
  const int tid = threadIdx.x;
  double ss = 0, st = 0;
  for (int k = tid; k < NP; k += 256) {
    ss += (double)dtw[k];
    st += (double)dtw[NP + k];
  }
  sh[tid] = ss; __syncthreads();
  for (int o = 128; o > 0; o >>= 1) { if (tid < o) sh[tid] += sh[tid + o]; __syncthreads(); }
  double sum_s = sh[0]; __syncthreads();
  sh[tid] = st; __syncthreads();
  for (int o = 128; o > 0; o >>= 1) { if (tid < o) sh[tid] += sh[tid + o]; __syncthreads(); }
  double sum_t = sh[0]; __syncthreads();

  float mean_s = (float)(sum_s / NP);
  float mean_t = (float)(sum_t / NP);

  double acc = 0;
  for (int k = tid; k < NP; k += 256) {
    float pred = dtw[k] / mean_s;
    float targ = dtw[NP + k] / mean_t;
    float d = pred - targ;
    float ad = fabsf(d);
    float v = ad < 1.f ? 0.5f * d * d : ad - 0.5f;
    acc += (double)v;
  }
  sh[tid] = acc; __syncthreads();
  for (int o = 128; o > 0; o >>= 1) { if (tid < o) sh[tid] += sh[tid + o]; __syncthreads(); }
  if (tid == 0) out[0] = (float)(sh[0] / NP);
}

extern "C" void kernel_launch(void* const* d_in, const int* in_sizes, int n_in,
                              void* d_out, int out_size, void* d_ws, size_t ws_size,
                              hipStream_t stream) {
  const float* student = (const float*)d_in[0];
  const float* teacher = (const float*)d_in[1];
  const float* gamma   = (const float*)d_in[2];
  float* ws = (float*)d_ws;

  const size_t cd_floats = (size_t)NPROB * CSZ;              // 9,732,096
  const size_t need = (cd_floats + 2 * NP + 2 * BB * TT) * sizeof(float);

  if (ws_size >= need) {
    float* Cd  = ws;
    float* dtw = ws + cd_floats;
    float* xnb = dtw + 2 * NP;
    xn_kernel<<<24, 256, 0, stream>>>(student, teacher, xnb);
    csq_kernel<<<dim3(NPAIR, 2), 256, 0, stream>>>(student, teacher, xnb, gamma, Cd);
    dp_kernel<<<NPROB, 64, 0, stream>>>(Cd, gamma, dtw);
    reduce_kernel<<<1, 256, 0, stream>>>(dtw, (float*)d_out);
  } else {
    float* dtw = ws;
    float* xnb = ws + 2 * NP;
    xn_kernel<<<24, 256, 0, stream>>>(student, teacher, xnb);
    sdtw_fused_kernel<<<dim3(NPAIR, 2), 256, 0, stream>>>(student, teacher, xnb, gamma, dtw);
    reduce_kernel<<<1, 256, 0, stream>>>(dtw, (float*)d_out);
  }
}

// Round 13
// 106.452 us; speedup vs baseline: 1.0358x; 1.0358x over previous
//
#include <hip/hip_runtime.h>

// SoftDtwRkdDistance: B=32, T=96, D=128, f32 in, scalar f32 out.
// Split design:
//   K0 xn:  row squared-norms.
//   K1 csq: r11-proven (61.5us): A+B panels in LDS with per-row slot rotation
//           (conflict-free ds_read_b128). C'=(xn_a+xn_b-2*dot)*rg2, diag-major.
//   K2 dp:  GHOST-CELL wave DP: each lane redundantly computes its neighbor's
//           cell so the serial chain is lane-local VALU only; the 2 shfls/step
//           feed the ghosts one step later (latency off the critical path).
//           4-deep prefetch, phase-split (B dead for d<=62 / d>=129).
//   K3 reduce: means + smooth-L1.
// Fallback: if ws too small for the 38 MB C buffer, run the round-3 fused kernel.

constexpr int TT = 96;
constexpr int DD = 128;
constexpr int BB = 32;
constexpr int NP = BB * BB;               // 1024
constexpr int NPAIR = BB * (BB + 1) / 2;  // 528
constexpr int NPROB = 2 * NPAIR;          // 1056
constexpr int CSZ = TT * TT;              // 9216 floats per problem
constexpr float FINF = 1e10f;
constexpr float LOG2E = 1.4426950408889634f;
constexpr float LN2 = 0.6931471805599453f;

__device__ __forceinline__ int tri_base(int a) {   // pairs with first index < a
  return a * BB - (a * (a - 1)) / 2;
}
__device__ __forceinline__ void tri_decode(int pr, int& a, int& b) {
  a = (int)((65.0f - sqrtf(4225.0f - 8.0f * (float)pr)) * 0.5f);
  while (tri_base(a + 1) <= pr) ++a;
  while (tri_base(a) > pr) --a;
  b = a + (pr - tri_base(a));
}
__device__ __forceinline__ int diag_base(int d) {
  return (d <= 95) ? ((d * (d + 1)) >> 1)
                   : 4656 + (((d - 96) * (287 - d)) >> 1);
}
// softmin in z''-domain, op order matches reference (up, left, diag)
__device__ __forceinline__ float smin2(float u, float lf, float dg) {
  float m = fmaxf(fmaxf(u, lf), dg);
  float s = __builtin_amdgcn_exp2f(u - m) + __builtin_amdgcn_exp2f(lf - m)
          + __builtin_amdgcn_exp2f(dg - m);
  return m + __builtin_amdgcn_logf(s);
}

// K0: row squared-norms xn[2][BB*TT]
__global__ void xn_kernel(const float* __restrict__ xs,
                          const float* __restrict__ xt,
                          float* __restrict__ xn) {
  int idx = blockIdx.x * 256 + threadIdx.x;
  if (idx >= 2 * BB * TT) return;
  int which = idx / (BB * TT);
  int row = idx - which * (BB * TT);
  const float* x = which ? xt : xs;
  const float4* xv = reinterpret_cast<const float4*>(x + (size_t)row * DD);
  float acc = 0.f;
#pragma unroll
  for (int k = 0; k < DD / 4; ++k) {
    float4 v = xv[k];
    acc = fmaf(v.x, v.x, acc);
    acc = fmaf(v.y, v.y, acc);
    acc = fmaf(v.z, v.z, acc);
    acc = fmaf(v.w, v.w, acc);
  }
  xn[idx] = acc;
}

// K1: C' in diag-major global layout. One 256-thread block per (pair, tensor).
// r11-proven: per-row slot-rotated LDS layout (conflict-free reads).
__global__ __launch_bounds__(256)
void csq_kernel(const float* __restrict__ xs,
                const float* __restrict__ xt,
                const float* __restrict__ xn,
                const float* __restrict__ gptr,
                float* __restrict__ Cd) {
  __shared__ __align__(16) float Cs[CSZ];   // staging aliases front (6912 floats)
  __shared__ float xna[TT];
  __shared__ float xnb[TT];

  const int pr = blockIdx.x;
  int a, b;
  tri_decode(pr, a, b);
  const int w = blockIdx.y;
  const float* x = w ? xt : xs;
  const float* xnw = xn + w * (BB * TT);
  const float* xa = x + (size_t)a * TT * DD;
  const float* xb = x + (size_t)b * TT * DD;
  const int tid = threadIdx.x;

  if (tid < TT) {
    xna[tid] = xnw[a * TT + tid];
    xnb[tid] = xnw[b * TT + tid];
  }

  // staged panels: [96 rows][9 float4 slots]; row t's logical k4 block lives
  // at slot (k4 + t/6) & 7 (slot 8 unused pad).
  float4* sa = reinterpret_cast<float4*>(Cs);          // A panel: 864 float4
  float4* sb = sa + TT * 9;                            // B panel: 864 float4

  const int wv = tid >> 6;
  const int lane = tid & 63;
  const int tx = (lane & 7) + (wv & 1) * 8;      // 0..15
  const int ty = (lane >> 3) + (wv >> 1) * 8;    // 0..15
  const int t0 = ty * 6, s0 = tx * 6;

  float acc[6][6];
#pragma unroll
  for (int r = 0; r < 6; ++r)
#pragma unroll
    for (int c = 0; c < 6; ++c) acc[r][c] = 0.f;

  const float4* ga = reinterpret_cast<const float4*>(xa);  // row stride 32
  const float4* gb = reinterpret_cast<const float4*>(xb);

  for (int d0 = 0; d0 < 4; ++d0) {     // 4 chunks of 8 float4 (32 k)
    __syncthreads();   // previous chunk's reads done before overwrite
#pragma unroll
    for (int it = 0; it < 3; ++it) {
      int idx = tid + it * 256;        // 0..767
      int t = idx >> 3, k4 = idx & 7;  // row, logical slot
      int slot = (k4 + (t / 6)) & 7;   // rotated storage slot
      sa[t * 9 + slot] = ga[t * 32 + d0 * 8 + k4];
      sb[t * 9 + slot] = gb[t * 32 + d0 * 8 + k4];
    }
    __syncthreads();
#pragma unroll
    for (int k4 = 0; k4 < 8; ++k4) {
      float4 av4[6], bv4[6];
      const int sA = (k4 + ty) & 7;    // rotated slot for this lane's A rows
      const int sB = (k4 + tx) & 7;    // rotated slot for this lane's B rows
#pragma unroll
      for (int r = 0; r < 6; ++r)
        av4[r] = sa[(t0 + r) * 9 + sA];
#pragma unroll
      for (int c = 0; c < 6; ++c)
        bv4[c] = sb[(s0 + c) * 9 + sB];
#pragma unroll
      for (int r = 0; r < 6; ++r)
#pragma unroll
        for (int c = 0; c < 6; ++c) {
          acc[r][c] = fmaf(av4[r].x, bv4[c].x, acc[r][c]);
          acc[r][c] = fmaf(av4[r].y, bv4[c].y, acc[r][c]);
          acc[r][c] = fmaf(av4[r].z, bv4[c].z, acc[r][c]);
          acc[r][c] = fmaf(av4[r].w, bv4[c].w, acc[r][c]);
        }
    }
  }
  __syncthreads();
  const float rg2 = -LOG2E / gptr[0];
#pragma unroll
  for (int r = 0; r < 6; ++r) {
    float xr = xna[t0 + r];
#pragma unroll
    for (int c = 0; c < 6; ++c) {
      float cv = xr + xnb[s0 + c] - 2.0f * acc[r][c];   // exact ref C
      Cs[(t0 + r) * TT + (s0 + c)] = cv * rg2;          // pre-scaled, row-major
    }
  }
  __syncthreads();

  // write-out: diag-major, coalesced; wave wv handles diagonals d ≡ wv (mod 4)
  const size_t qb = (size_t)(w * NPAIR + pr) * CSZ;
  for (int d = wv; d < 2 * TT - 1; d += 4) {
    int s = d <= 95 ? 0 : d - 95;
    int len = d <= 95 ? d + 1 : 191 - d;
    int base = diag_base(d);
    if (lane < len) {
      int i = s + lane;
      Cd[qb + base + lane] = Cs[i * TT + (d - i)];
    }
    if (len > 64 && lane < len - 64) {
      int i = s + 64 + lane;
      Cd[qb + base + 64 + lane] = Cs[i * TT + (d - i)];
    }
  }
}

// K2: GHOST-CELL DP. One wave per problem q = w*528 + pr. No LDS.
// Lane l holds: main cells pos l (A) and pos 64+l (B), plus ghost copies of
// pos l∓1 (GA) and pos 63+l / 65+l (GB). Main updates are lane-local; shfls
// (hA,hB) feed next step's ghost updates -> off the critical path.
#define PREF(dn, sA, sG, sB, sH) do {                                    \
    if ((dn) <= 190) {                                                   \
      int nb = diag_base(dn);                                            \
      int iA = nb + l;                 if (iA > CSZ - 1) iA = CSZ - 1;   \
      sA = cb[iA];                                                       \
      int iG = ((dn) <= 95) ? (nb + l - 1) : (nb + l + 1);               \
      if (iG > CSZ - 1) iG = CSZ - 1;                                    \
      sG = cb[iG];                                                       \
      if ((dn) >= 63 && (dn) <= 128) {                                   \
        int iB = nb + 64 + l;          if (iB > CSZ - 1) iB = CSZ - 1;   \
        sB = cb[iB];                                                     \
        int iH = ((dn) <= 95) ? (nb + 63 + l) : (nb + 65 + l);           \
        if (iH > CSZ - 1) iH = CSZ - 1;                                  \
        sH = cb[iH];                                                     \
      }                                                                  \
    }                                                                    \
  } while (0)

#define GST_RN(d, sA, sG, sB, sH) do {  /* rising, B dead (d<=62) */     \
    float cA = sA, cG = sG;                                              \
    PREF((d) + 4, sA, sG, sB, sH);                                       \
    float nA = cA + smin2(GA1, A1, GA2);                                 \
    float nG = cG + smin2(hA, GA1, phA);                                 \
    nA = (l <= (d)) ? nA : NEGI;                                         \
    nG = (l >= 1 && l - 1 <= (d)) ? nG : NEGI;                           \
    A2 = A1; GA2 = GA1; A1 = nA; GA1 = nG;                               \
    phA = hA; hA = __shfl(GA1, lm1);                                     \
  } while (0)

#define GST_RF(d, sA, sG, sB, sH) do {  /* rising, full */               \
    float cA = sA, cG = sG, cB = sB, cH = sH;                            \
    PREF((d) + 4, sA, sG, sB, sH);                                       \
    float nA = cA + smin2(GA1, A1, GA2);                                 \
    float nB = cB + smin2(GB1, B1, GB2);                                 \
    float nG = cG + smin2(hA, GA1, phA);                                 \
    float hBe = l0 ? hA : hB, phBe = l0 ? phA : phB;                     \
    float nH = cH + smin2(hBe, GB1, phBe);                               \
    nA = (l <= (d)) ? nA : NEGI;                                         \
    nB = (64 + l <= (d)) ? nB : NEGI;                                    \
    nG = (l >= 1 && l - 1 <= (d)) ? nG : NEGI;                           \
    nH = (63 + l <= (d)) ? nH : NEGI;                                    \
    A2 = A1; B2 = B1; GA2 = GA1; GB2 = GB1;                              \
    A1 = nA; B1 = nB; GA1 = nG; GB1 = nH;                                \
    phA = hA; phB = hB;                                                  \
    hA = __shfl(GA1, lm1); hB = __shfl(GB1, lm1);                        \
  } while (0)

#define GST_FF(d, sA, sG, sB, sH) do {  /* falling, full */              \
    float cA = sA, cG = sG, cB = sB, cH = sH;                            \
    PREF((d) + 4, sA, sG, sB, sH);                                       \
    float nA = cA + smin2(A1, GA1, GA2);                                 \
    float nB = cB + smin2(B1, GB1, GB2);                                 \
    float hAe = l63 ? hB : hA, phAe = l63 ? phB : phA;                   \
    float nG = cG + smin2(GA1, hAe, phAe);                               \
    float nH = cH + smin2(GB1, hB, phB);                                 \
    nA = (l < 191 - (d)) ? nA : NEGI;                                    \
    nB = (64 + l < 191 - (d)) ? nB : NEGI;                               \
    nG = (l + 1 < 191 - (d)) ? nG : NEGI;                                \
    nH = (65 + l < 191 - (d)) ? nH : NEGI;                               \
    GA2 = GA1; GB2 = GB1;                                                \
    A1 = nA; B1 = nB; GA1 = nG; GB1 = nH;                                \
    phA = hA; phB = hB;                                                  \
    hA = __shfl(GA1, lp1); hB = __shfl(GB1, lp1);                        \
  } while (0)

#define GST_FN(d, sA, sG, sB, sH) do {  /* falling, B dead (d>=129) */   \
    float cA = sA, cG = sG;                                              \
    PREF((d) + 4, sA, sG, sB, sH);                                       \
    float nA = cA + smin2(A1, GA1, GA2);                                 \
    float hAe = l63 ? NEGI : hA, phAe = l63 ? NEGI : phA;                \
    float nG = cG + smin2(GA1, hAe, phAe);                               \
    nA = (l < 191 - (d)) ? nA : NEGI;                                    \
    nG = (l + 1 < 191 - (d)) ? nG : NEGI;                                \
    GA2 = GA1; A1 = nA; GA1 = nG;                                        \
    phA = hA; hA = __shfl(GA1, lp1);                                     \
  } while (0)

__global__ __launch_bounds__(64)
void dp_kernel(const float* __restrict__ Cd,
               const float* __restrict__ gptr,
               float* __restrict__ dtw) {
  const int q = blockIdx.x;
  const int l = threadIdx.x;
  const float gamma = gptr[0];
  const float rg2 = -LOG2E / gamma;
  const float NEGI = FINF * rg2;          // invalid cell in z''-domain
  const float* __restrict__ cb = Cd + (size_t)q * CSZ;
  const int lp1 = (l + 1) & 63, lm1 = (l + 63) & 63;
  const bool l0 = (l == 0), l63 = (l == 63);

  // prefetch slots (slot = (d-1)&3), 4 values each
  float s0A = NEGI, s0G = NEGI, s0B = NEGI, s0H = NEGI;
  float s1A = NEGI, s1G = NEGI, s1B = NEGI, s1H = NEGI;
  float s2A = NEGI, s2G = NEGI, s2B = NEGI, s2H = NEGI;
  float s3A = NEGI, s3G = NEGI, s3B = NEGI, s3H = NEGI;
  PREF(1, s0A, s0G, s0B, s0H);
  PREF(2, s1A, s1G, s1B, s1H);
  PREF(3, s2A, s2G, s2B, s2H);
  PREF(4, s3A, s3G, s3B, s3H);

  // d = 0 peel + ghost init: A1 = pos l @ 0; GA1 = pos l-1 @ 0; hA = pos l-2 @ 0
  float A1 = l0 ? cb[0] : NEGI;
  float A2 = NEGI, B1 = NEGI, B2 = NEGI;
  float GA1 = (l == 1) ? cb[0] : NEGI;
  float GA2 = NEGI, GB1 = NEGI, GB2 = NEGI;
  float hA = (l == 2) ? cb[0] : NEGI;
  float hB = NEGI, phA = NEGI, phB = NEGI;

  // rising, B dead: d = 1..60 (15 groups), peel 61,62
  for (int g = 0; g < 15; ++g) {
    int d = 1 + g * 4;
    GST_RN(d,     s0A, s0G, s0B, s0H);
    GST_RN(d + 1, s1A, s1G, s1B, s1H);
    GST_RN(d + 2, s2A, s2G, s2B, s2H);
    GST_RN(d + 3, s3A, s3G, s3B, s3H);
  }
  GST_RN(61, s0A, s0G, s0B, s0H);
  GST_RN(62, s1A, s1G, s1B, s1H);

  // rising, full: 63, 64, then 65..92 (7 groups), peel 93,94,95
  GST_RF(63, s2A, s2G, s2B, s2H);
  GST_RF(64, s3A, s3G, s3B, s3H);
  for (int g = 0; g < 7; ++g) {
    int d = 65 + g * 4;
    GST_RF(d,     s0A, s0G, s0B, s0H);
    GST_RF(d + 1, s1A, s1G, s1B, s1H);
    GST_RF(d + 2, s2A, s2G, s2B, s2H);
    GST_RF(d + 3, s3A, s3G, s3B, s3H);
  }
  GST_RF(93, s0A, s0G, s0B, s0H);
  GST_RF(94, s1A, s1G, s1B, s1H);
  GST_RF(95, s2A, s2G, s2B, s2H);

  // d = 96 pivot: main via in-chain shfls (one-time), then ghost re-init
  {
    float cA = s3A, cB = s3B;
    PREF(100, s3A, s3G, s3B, s3H);
    float rA1 = __shfl(A1, lp1), rB1 = __shfl(B1, lp1);
    float lfA = l63 ? rB1 : rA1;                 // pos l+1 @ 95
    float nA = cA + smin2(A1, lfA, A2);
    float nB = cB + smin2(B1, rB1, B2);
    nA = (l < 95) ? nA : NEGI;
    nB = (64 + l < 95) ? nB : NEGI;
    GA2 = lfA;                                   // pos l+1 @ 95
    GB2 = (65 + l <= 95) ? rB1 : NEGI;           // pos 65+l @ 95
    float rA1n = __shfl(nA, lp1), rB1n = __shfl(nB, lp1);
    GA1 = l63 ? rB1n : rA1n;                     // pos l+1 @ 96
    GA1 = (l + 1 < 95) ? GA1 : NEGI;
    GB1 = (65 + l < 95) ? rB1n : NEGI;           // pos 65+l @ 96
    phA = __shfl(GA2, lp1);                      // pos l+2 @ 95
    phB = __shfl(GB2, lp1);                      // pos 66+l @ 95 (lane63: pos 65)
    hA  = __shfl(GA1, lp1);                      // pos l+2 @ 96
    hB  = __shfl(GB1, lp1);                      // pos 66+l @ 96 (lane63: pos 65)
    A1 = nA; B1 = nB;
  }

  // falling, full: d = 97..128 (8 groups)
  for (int g = 0; g < 8; ++g) {
    int d = 97 + g * 4;
    GST_FF(d,     s0A, s0G, s0B, s0H);
    GST_FF(d + 1, s1A, s1G, s1B, s1H);
    GST_FF(d + 2, s2A, s2G, s2B, s2H);
    GST_FF(d + 3, s3A, s3G, s3B, s3H);
  }
  // falling, B dead: d = 129..188 (15 groups), peel 189,190
  for (int g = 0; g < 15; ++g) {
    int d = 129 + g * 4;
    GST_FN(d,     s0A, s0G, s0B, s0H);
    GST_FN(d + 1, s1A, s1G, s1B, s1H);
    GST_FN(d + 2, s2A, s2G, s2B, s2H);
    GST_FN(d + 3, s3A, s3G, s3B, s3H);
  }
  GST_FN(189, s0A, s0G, s0B, s0H);
  GST_FN(190, s1A, s1G, s1B, s1H);

  // cell (95,95) = position 0 of diag 190 -> lane 0, A1
  if (l0) {
    int w = q >= NPAIR ? 1 : 0;
    int pr = q - w * NPAIR;
    int a, b;
    tri_decode(pr, a, b);
    float v = A1 * (-gamma * LN2);       // back to r-domain
    dtw[w * NP + a * BB + b] = v;
    dtw[w * NP + b * BB + a] = v;
  }
}

// ---------------- Fallback fused kernel (round-3, proven) ----------------
__global__ __launch_bounds__(256)
void sdtw_fused_kernel(const float* __restrict__ xs,
                       const float* __restrict__ xt,
                       const float* __restrict__ xn,
                       const float* __restrict__ gptr,
                       float* __restrict__ dtw) {
  __shared__ __align__(16) float Cs[TT * TT];
  __shared__ float xna[TT];
  __shared__ float xnb[TT];

  const int pr = blockIdx.x;
  int a, b;
  tri_decode(pr, a, b);
  const int w = blockIdx.y;
  const float* x = w ? xt : xs;
  const float* xnw = xn + w * (BB * TT);
  const float* xa = x + (size_t)a * TT * DD;
  const float* xb = x + (size_t)b * TT * DD;
  const int tid = threadIdx.x;

  if (tid < TT) {
    xna[tid] = xnw[a * TT + tid];
    xnb[tid] = xnw[b * TT + tid];
  }
  constexpr int SROW = 36;
  float* xa_s = Cs;
  float* xb_s = Cs + TT * SROW;
  const int wv = tid >> 6;
  const int lane = tid & 63;
  const int tx = (lane & 7) + (wv & 1) * 8;
  const int ty = (lane >> 3) + (wv >> 1) * 8;
  const int t0 = ty * 6, s0 = tx * 6;
  float acc[6][6];
#pragma unroll
  for (int r = 0; r < 6; ++r)
#pragma unroll
    for (int c = 0; c < 6; ++c) acc[r][c] = 0.f;
  for (int d0 = 0; d0 < DD; d0 += 32) {
    __syncthreads();
    const float4* ga = reinterpret_cast<const float4*>(xa + d0);
    const float4* gb = reinterpret_cast<const float4*>(xb + d0);
    float4* sa = reinterpret_cast<float4*>(xa_s);
    float4* sb = reinterpret_cast<float4*>(xb_s);
#pragma unroll
    for (int it = 0; it < 3; ++it) {
      int idx = tid + it * 256;
      int t = idx >> 3, k4 = idx & 7;
      sa[t * (SROW / 4) + k4] = ga[t * (DD / 4) + k4];
      sb[t * (SROW / 4) + k4] = gb[t * (DD / 4) + k4];
    }
    __syncthreads();
#pragma unroll
    for (int k4 = 0; k4 < 8; ++k4) {
      float4 av4[6], bv4[6];
#pragma unroll
      for (int r = 0; r < 6; ++r)
        av4[r] = reinterpret_cast<const float4*>(xa_s + (t0 + r) * SROW)[k4];
#pragma unroll
      for (int c = 0; c < 6; ++c)
        bv4[c] = reinterpret_cast<const float4*>(xb_s + (s0 + c) * SROW)[k4];
#pragma unroll
      for (int r = 0; r < 6; ++r)
#pragma unroll
        for (int c = 0; c < 6; ++c) {
          acc[r][c] = fmaf(av4[r].x, bv4[c].x, acc[r][c]);
          acc[r][c] = fmaf(av4[r].y, bv4[c].y, acc[r][c]);
          acc[r][c] = fmaf(av4[r].z, bv4[c].z, acc[r][c]);
          acc[r][c] = fmaf(av4[r].w, bv4[c].w, acc[r][c]);
        }
    }
  }
  __syncthreads();
#pragma unroll
  for (int r = 0; r < 6; ++r) {
    float xr = xna[t0 + r];
#pragma unroll
    for (int c = 0; c < 6; ++c)
      Cs[(t0 + r) * TT + (s0 + c)] = xr + xnb[s0 + c] - 2.0f * acc[r][c];
  }
  __syncthreads();
  if (tid >= 64) return;

  const float gamma = gptr[0];
  const float rg = -1.0f / gamma;
  const int lm1 = (lane + 63) & 63;
  float A1 = FINF, B1 = FINF, A2 = FINF, B2 = FINF;
  for (int d = 0; d < 2 * TT - 1; ++d) {
    int jA = d - lane;
    bool vA = (jA >= 0) && (jA < TT);
    float cA = Cs[vA ? lane * TT + jA : 0];
    int iB = 64 + lane;
    int jB = d - iB;
    bool vB = (lane < 32) && (jB >= 0) && (jB < TT);
    float cB = Cs[vB ? iB * TT + jB : 0];
    float rA1 = __shfl(A1, lm1);
    float rB1 = __shfl(B1, lm1);
    float rA2 = __shfl(A2, lm1);
    float rB2 = __shfl(B2, lm1);
    const bool l0 = (lane == 0);
    float upA = l0 ? FINF : rA1;
    float dgA = l0 ? FINF : rA2;
    float upB = l0 ? rA1 : rB1;
    float dgB = l0 ? rA2 : rB2;
    float z0 = upA * rg, z1 = A1 * rg, z2 = dgA * rg;
    float m = fmaxf(fmaxf(z0, z1), z2);
    float s = expf(z0 - m) + expf(z1 - m) + expf(z2 - m);
    float sminA = -gamma * (m + logf(s));
    if (d == 0) sminA = 0.f;
    float y0 = upB * rg, y1 = B1 * rg, y2 = dgB * rg;
    float mb = fmaxf(fmaxf(y0, y1), y2);
    float sb2 = expf(y0 - mb) + expf(y1 - mb) + expf(y2 - mb);
    float sminB = -gamma * (mb + logf(sb2));
    float nA = vA ? cA + sminA : FINF;
    float nB = vB ? cB + sminB : FINF;
    A2 = A1; B2 = B1; A1 = nA; B1 = nB;
  }
  if (lane == 31) {
    float v = B1;
    dtw[w * NP + a * BB + b] = v;
    dtw[w * NP + b * BB + a] = v;
  }
}

// K3: means + normalized smooth-L1 (single block).
__global__ void reduce_kernel(const float* __restrict__ dtw,
                              float* __restrict__ out) {
  __shared__ double sh[256];
  const int tid = threadIdx.x;
  double ss = 0, st = 0;
  for (int k = tid; k < NP; k += 256) {
    ss += (double)dtw[k];
    st += (double)dtw[NP + k];
  }
  sh[tid] = ss; __syncthreads();
  for (int o = 128; o > 0; o >>= 1) { if (tid < o) sh[tid] += sh[tid + o]; __syncthreads(); }
  double sum_s = sh[0]; __syncthreads();
  sh[tid] = st; __syncthreads();
  for (int o = 128; o > 0; o >>= 1) { if (tid < o) sh[tid] += sh[tid + o]; __syncthreads(); }
  double sum_t = sh[0]; __syncthreads();

  float mean_s = (float)(sum_s / NP);
  float mean_t = (float)(sum_t / NP);

  double acc = 0;
  for (int k = tid; k < NP; k += 256) {
    float pred = dtw[k] / mean_s;
    float targ = dtw[NP + k] / mean_t;
    float d = pred - targ;
    float ad = fabsf(d);
    float v = ad < 1.f ? 0.5f * d * d : ad - 0.5f;
    acc += (double)v;
  }
  sh[tid] = acc; __syncthreads();
  for (int o = 128; o > 0; o >>= 1) { if (tid < o) sh[tid] += sh[tid + o]; __syncthreads(); }
  if (tid == 0) out[0] = (float)(sh[0] / NP);
}

extern "C" void kernel_launch(void* const* d_in, const int* in_sizes, int n_in,
                              void* d_out, int out_size, void* d_ws, size_t ws_size,
                              hipStream_t stream) {
  const float* student = (const float*)d_in[0];
  const float* teacher = (const float*)d_in[1];
  const float* gamma   = (const float*)d_in[2];
  float* ws = (float*)d_ws;

  const size_t cd_floats = (size_t)NPROB * CSZ;              // 9,732,096
  const size_t need = (cd_floats + 2 * NP + 2 * BB * TT) * sizeof(float);

  if (ws_size >= need) {
    float* Cd  = ws;
    float* dtw = ws + cd_floats;
    float* xnb = dtw + 2 * NP;
    xn_kernel<<<24, 256, 0, stream>>>(student, teacher, xnb);
    csq_kernel<<<dim3(NPAIR, 2), 256, 0, stream>>>(student, teacher, xnb, gamma, Cd);
    dp_kernel<<<NPROB, 64, 0, stream>>>(Cd, gamma, dtw);
    reduce_kernel<<<1, 256, 0, stream>>>(dtw, (float*)d_out);
  } else {
    float* dtw = ws;
    float* xnb = ws + 2 * NP;
    xn_kernel<<<24, 256, 0, stream>>>(student, teacher, xnb);
    sdtw_fused_kernel<<<dim3(NPAIR, 2), 256, 0, stream>>>(student, teacher, xnb, gamma, dtw);
    reduce_kernel<<<1, 256, 0, stream>>>(dtw, (float*)d_out);
  }
}

// Round 14
// 98.024 us; speedup vs baseline: 1.1249x; 1.0860x over previous
//
#include <hip/hip_runtime.h>

// SoftDtwRkdDistance: B=32, T=96, D=128, f32 in, scalar f32 out.
// Split design (r11 best-known, consolidated):
//   K1 csq: A+B panels in LDS with per-row slot rotation (conflict-free
//           ds_read_b128); xn row-norms computed IN-BLOCK (bit-identical
//           chain; saves the xn kernel launch). C'=(xn_a+xn_b-2*dot)*rg2,
//           diag-major global layout.
//   K2 dp:  one wave per problem; 4-deep register prefetch, 2 shfls/diag,
//           compact phase-split loops (B-side skipped where provably dead).
//   K3 reduce: means + smooth-L1.
// Fallback: if ws too small for the 38 MB C buffer, run the round-3 fused kernel.

constexpr int TT = 96;
constexpr int DD = 128;
constexpr int BB = 32;
constexpr int NP = BB * BB;               // 1024
constexpr int NPAIR = BB * (BB + 1) / 2;  // 528
constexpr int NPROB = 2 * NPAIR;          // 1056
constexpr int CSZ = TT * TT;              // 9216 floats per problem
constexpr float FINF = 1e10f;
constexpr float LOG2E = 1.4426950408889634f;
constexpr float LN2 = 0.6931471805599453f;

__device__ __forceinline__ int tri_base(int a) {   // pairs with first index < a
  return a * BB - (a * (a - 1)) / 2;
}
__device__ __forceinline__ void tri_decode(int pr, int& a, int& b) {
  a = (int)((65.0f - sqrtf(4225.0f - 8.0f * (float)pr)) * 0.5f);
  while (tri_base(a + 1) <= pr) ++a;
  while (tri_base(a) > pr) --a;
  b = a + (pr - tri_base(a));
}
__device__ __forceinline__ int diag_base(int d) {
  return (d <= 95) ? ((d * (d + 1)) >> 1)
                   : 4656 + (((d - 96) * (287 - d)) >> 1);
}
// softmin in z''-domain, op order matches reference (up, left, diag)
__device__ __forceinline__ float smin2(float u, float lf, float dg) {
  float m = fmaxf(fmaxf(u, lf), dg);
  float s = __builtin_amdgcn_exp2f(u - m) + __builtin_amdgcn_exp2f(lf - m)
          + __builtin_amdgcn_exp2f(dg - m);
  return m + __builtin_amdgcn_logf(s);
}
// row squared-norm, bit-identical to the original xn_kernel chain
__device__ __forceinline__ float row_norm(const float* __restrict__ row) {
  const float4* xv = reinterpret_cast<const float4*>(row);
  float acc = 0.f;
#pragma unroll
  for (int k = 0; k < DD / 4; ++k) {
    float4 v = xv[k];
    acc = fmaf(v.x, v.x, acc);
    acc = fmaf(v.y, v.y, acc);
    acc = fmaf(v.z, v.z, acc);
    acc = fmaf(v.w, v.w, acc);
  }
  return acc;
}

// K0 (fallback path only): row squared-norms xn[2][BB*TT]
__global__ void xn_kernel(const float* __restrict__ xs,
                          const float* __restrict__ xt,
                          float* __restrict__ xn) {
  int idx = blockIdx.x * 256 + threadIdx.x;
  if (idx >= 2 * BB * TT) return;
  int which = idx / (BB * TT);
  int row = idx - which * (BB * TT);
  const float* x = which ? xt : xs;
  xn[idx] = row_norm(x + (size_t)row * DD);
}

// K1: C' in diag-major global layout. One 256-thread block per (pair, tensor).
// r11-proven: per-row slot-rotated LDS layout (conflict-free reads); norms in-block.
__global__ __launch_bounds__(256)
void csq_kernel(const float* __restrict__ xs,
                const float* __restrict__ xt,
                const float* __restrict__ gptr,
                float* __restrict__ Cd) {
  __shared__ __align__(16) float Cs[CSZ];   // staging aliases front (6912 floats)
  __shared__ float xna[TT];
  __shared__ float xnb[TT];

  const int pr = blockIdx.x;
  int a, b;
  tri_decode(pr, a, b);
  const int w = blockIdx.y;
  const float* x = w ? xt : xs;
  const float* xa = x + (size_t)a * TT * DD;
  const float* xb = x + (size_t)b * TT * DD;
  const int tid = threadIdx.x;

  // in-block row norms (bit-identical chain); read only in the epilogue,
  // which is after several barriers.
  if (tid < TT) {
    xna[tid] = row_norm(xa + (size_t)tid * DD);
  } else if (tid < 2 * TT) {
    xnb[tid - TT] = row_norm(xb + (size_t)(tid - TT) * DD);
  }

  // staged panels: [96 rows][9 float4 slots]; row t's logical k4 block lives
  // at slot (k4 + t/6) & 7 (slot 8 unused pad).
  float4* sa = reinterpret_cast<float4*>(Cs);          // A panel: 864 float4
  float4* sb = sa + TT * 9;                            // B panel: 864 float4

  const int wv = tid >> 6;
  const int lane = tid & 63;
  const int tx = (lane & 7) + (wv & 1) * 8;      // 0..15
  const int ty = (lane >> 3) + (wv >> 1) * 8;    // 0..15
  const int t0 = ty * 6, s0 = tx * 6;

  float acc[6][6];
#pragma unroll
  for (int r = 0; r < 6; ++r)
#pragma unroll
    for (int c = 0; c < 6; ++c) acc[r][c] = 0.f;

  const float4* ga = reinterpret_cast<const float4*>(xa);  // row stride 32
  const float4* gb = reinterpret_cast<const float4*>(xb);

  for (int d0 = 0; d0 < 4; ++d0) {     // 4 chunks of 8 float4 (32 k)
    __syncthreads();   // previous chunk's reads done before overwrite
#pragma unroll
    for (int it = 0; it < 3; ++it) {
      int idx = tid + it * 256;        // 0..767
      int t = idx >> 3, k4 = idx & 7;  // row, logical slot
      int slot = (k4 + (t / 6)) & 7;   // rotated storage slot
      sa[t * 9 + slot] = ga[t * 32 + d0 * 8 + k4];
      sb[t * 9 + slot] = gb[t * 32 + d0 * 8 + k4];
    }
    __syncthreads();
#pragma unroll
    for (int k4 = 0; k4 < 8; ++k4) {
      float4 av4[6], bv4[6];
      const int sA = (k4 + ty) & 7;    // rotated slot for this lane's A rows
      const int sB = (k4 + tx) & 7;    // rotated slot for this lane's B rows
#pragma unroll
      for (int r = 0; r < 6; ++r)
        av4[r] = sa[(t0 + r) * 9 + sA];
#pragma unroll
      for (int c = 0; c < 6; ++c)
        bv4[c] = sb[(s0 + c) * 9 + sB];
#pragma unroll
      for (int r = 0; r < 6; ++r)
#pragma unroll
        for (int c = 0; c < 6; ++c) {
          acc[r][c] = fmaf(av4[r].x, bv4[c].x, acc[r][c]);
          acc[r][c] = fmaf(av4[r].y, bv4[c].y, acc[r][c]);
          acc[r][c] = fmaf(av4[r].z, bv4[c].z, acc[r][c]);
          acc[r][c] = fmaf(av4[r].w, bv4[c].w, acc[r][c]);
        }
    }
  }
  __syncthreads();
  const float rg2 = -LOG2E / gptr[0];
#pragma unroll
  for (int r = 0; r < 6; ++r) {
    float xr = xna[t0 + r];
#pragma unroll
    for (int c = 0; c < 6; ++c) {
      float cv = xr + xnb[s0 + c] - 2.0f * acc[r][c];   // exact ref C
      Cs[(t0 + r) * TT + (s0 + c)] = cv * rg2;          // pre-scaled, row-major
    }
  }
  __syncthreads();

  // write-out: diag-major, coalesced; wave wv handles diagonals d ≡ wv (mod 4)
  const size_t qb = (size_t)(w * NPAIR + pr) * CSZ;
  for (int d = wv; d < 2 * TT - 1; d += 4) {
    int s = d <= 95 ? 0 : d - 95;
    int len = d <= 95 ? d + 1 : 191 - d;
    int base = diag_base(d);
    if (lane < len) {
      int i = s + lane;
      Cd[qb + base + lane] = Cs[i * TT + (d - i)];
    }
    if (len > 64 && lane < len - 64) {
      int i = s + 64 + lane;
      Cd[qb + base + 64 + lane] = Cs[i * TT + (d - i)];
    }
  }
}

// K2: DP. One wave per problem q = w*528 + pr. No LDS.
// 4-deep prefetch (slot (d-1)&3), 2 shfls/diag via shadow regs,
// compact phase-split: B-side skipped where provably NEGI.
#define ST_R(d, qa, qb) do {                                             \
    float cA = qa, cB = qb;                                              \
    { int dn = (d) + 4;                                                  \
      if (dn <= 190) { int nb = diag_base(dn);                           \
        qa = cb[nb + l]; qb = cb[nb + 64 + l]; } }                       \
    float rA1 = __shfl(A1, lm1), rB1 = __shfl(B1, lm1);                  \
    float upA = l0 ? NEGI : rA1;                                         \
    float dgA = l0 ? NEGI : pA1;                                         \
    float upB = l0 ? rA1 : rB1;                                          \
    float dgB = l0 ? pA1 : pB1;                                          \
    float nA = cA + smin2(upA, A1, dgA);                                 \
    float nB = cB + smin2(upB, B1, dgB);                                 \
    A2 = A1; B2 = B1;                                                    \
    A1 = (l < (d) + 1) ? nA : NEGI;                                      \
    B1 = (64 + l < (d) + 1) ? nB : NEGI;                                 \
    pA1 = rA1; pB1 = rB1;                                                \
  } while (0)

#define ST_RN(d, qa, qb) do {  /* rising, B provably dead (d<=63) */     \
    float cA = qa;                                                       \
    { int dn = (d) + 4;                                                  \
      if (dn <= 190) { int nb = diag_base(dn);                           \
        qa = cb[nb + l]; qb = cb[nb + 64 + l]; } }                       \
    float rA1 = __shfl(A1, lm1);                                         \
    float upA = l0 ? NEGI : rA1;                                         \
    float dgA = l0 ? NEGI : pA1;                                         \
    float nA = cA + smin2(upA, A1, dgA);                                 \
    A2 = A1;                                                             \
    A1 = (l < (d) + 1) ? nA : NEGI;                                      \
    pA1 = rA1;                                                           \
  } while (0)

#define ST_F(d, qa, qb) do {                                             \
    float cA = qa, cB = qb;                                              \
    { int dn = (d) + 4;                                                  \
      if (dn <= 190) { int nb = diag_base(dn); qa = cb[nb + l];          \
        if (dn <= 128) qb = cb[nb + 64 + l]; } }                         \
    float rA1 = __shfl(A1, lp1), rB1 = __shfl(B1, lp1);                  \
    float lfA = l63 ? rB1 : rA1;                                         \
    float dgA = l63 ? pB1 : pA1;                                         \
    float nA = cA + smin2(A1, lfA, dgA);                                 \
    float nB = cB + smin2(B1, rB1, pB1);                                 \
    A1 = (l < 191 - (d)) ? nA : NEGI;                                    \
    B1 = (64 + l < 191 - (d)) ? nB : NEGI;                               \
    pA1 = rA1; pB1 = rB1;                                                \
  } while (0)

#define ST_FN(d, qa, qb) do {  /* falling, B provably dead (d>=129) */   \
    float cA = qa;                                                       \
    { int dn = (d) + 4;                                                  \
      if (dn <= 190) { int nb = diag_base(dn); qa = cb[nb + l]; } }      \
    float rA1 = __shfl(A1, lp1);                                         \
    float lfA = l63 ? NEGI : rA1;                                        \
    float dgA = l63 ? NEGI : pA1;                                        \
    float nA = cA + smin2(A1, lfA, dgA);                                 \
    A1 = (l < 191 - (d)) ? nA : NEGI;                                    \
    pA1 = rA1;                                                           \
  } while (0)

__global__ __launch_bounds__(64)
void dp_kernel(const float* __restrict__ Cd,
               const float* __restrict__ gptr,
               float* __restrict__ dtw) {
  const int q = blockIdx.x;
  const int l = threadIdx.x;
  const float gamma = gptr[0];
  const float rg2 = -LOG2E / gamma;
  const float NEGI = FINF * rg2;          // invalid cell in z''-domain
  const float* __restrict__ cb = Cd + (size_t)q * CSZ;
  const int lp1 = (l + 1) & 63, lm1 = (l + 63) & 63;
  const bool l0 = (l == 0), l63 = (l == 63);

  // prefetch queue: slot (d-1)&3; preload diagonals 1..4
  float q0A, q0B, q1A, q1B, q2A, q2B, q3A, q3B;
  {
    int b1 = diag_base(1), b2 = diag_base(2), b3 = diag_base(3), b4 = diag_base(4);
    q0A = cb[b1 + l]; q0B = cb[b1 + 64 + l];
    q1A = cb[b2 + l]; q1B = cb[b2 + 64 + l];
    q2A = cb[b3 + l]; q2B = cb[b3 + 64 + l];
    q3A = cb[b4 + l]; q3B = cb[b4 + 64 + l];
  }

  // d=0 peel: r(0,0)'' = C''(0,0)
  float A1 = l0 ? cb[0] : NEGI;
  float B1 = NEGI, A2 = NEGI, B2 = NEGI;
  float pA1 = NEGI, pB1 = NEGI;   // shadow: last iter's shfl(A1/B1)

  // rising, B dead: d = 1..60 (15 groups), peel 61,62,63
  for (int g = 0; g < 15; ++g) {
    int d = 1 + g * 4;
    ST_RN(d,     q0A, q0B);
    ST_RN(d + 1, q1A, q1B);
    ST_RN(d + 2, q2A, q2B);
    ST_RN(d + 3, q3A, q3B);
  }
  ST_RN(61, q0A, q0B);
  ST_RN(62, q1A, q1B);
  ST_RN(63, q2A, q2B);

  // rising, full: d = 64, 65..92 (7 groups), peel 93,94,95
  ST_R(64, q3A, q3B);
  for (int g = 0; g < 7; ++g) {
    int d = 65 + g * 4;
    ST_R(d,     q0A, q0B);
    ST_R(d + 1, q1A, q1B);
    ST_R(d + 2, q2A, q2B);
    ST_R(d + 3, q3A, q3B);
  }
  ST_R(93, q0A, q0B);
  ST_R(94, q1A, q1B);
  ST_R(95, q2A, q2B);

  // d = 96 boundary: offsets (0, +1, 0); consumes q3, prefetches 100
  {
    float cA = q3A, cB = q3B;
    int nb = diag_base(100);
    q3A = cb[nb + l]; q3B = cb[nb + 64 + l];
    float rA1 = __shfl(A1, lp1), rB1 = __shfl(B1, lp1);
    float lfA = l63 ? rB1 : rA1;
    float lfB = rB1;
    float nA = cA + smin2(A1, lfA, A2);
    float nB = cB + smin2(B1, lfB, B2);
    A1 = (l < 95) ? nA : NEGI;          // len = 95
    B1 = (64 + l < 95) ? nB : NEGI;
    pA1 = rA1; pB1 = rB1;
  }

  // falling, full: d = 97..128 (8 groups)
  for (int g = 0; g < 8; ++g) {
    int d = 97 + g * 4;
    ST_F(d,     q0A, q0B);
    ST_F(d + 1, q1A, q1B);
    ST_F(d + 2, q2A, q2B);
    ST_F(d + 3, q3A, q3B);
  }
  // falling, B dead: d = 129..188 (15 groups), peel 189,190
  for (int g = 0; g < 15; ++g) {
    int d = 129 + g * 4;
    ST_FN(d,     q0A, q0B);
    ST_FN(d + 1, q1A, q1B);
    ST_FN(d + 2, q2A, q2B);
    ST_FN(d + 3, q3A, q3B);
  }
  ST_FN(189, q0A, q0B);
  ST_FN(190, q1A, q1B);

  // cell (95,95) = position 0 of diag 190 -> lane 0, A1
  if (l0) {
    int w = q >= NPAIR ? 1 : 0;
    int pr = q - w * NPAIR;
    int a, b;
    tri_decode(pr, a, b);
    float v = A1 * (-gamma * LN2);       // back to r-domain
    dtw[w * NP + a * BB + b] = v;
    dtw[w * NP + b * BB + a] = v;
  }
}

// ---------------- Fallback fused kernel (round-3, proven) ----------------
__global__ __launch_bounds__(256)
void sdtw_fused_kernel(const float* __restrict__ xs,
                       const float* __restrict__ xt,
                       const float* __restrict__ xn,
                       const float* __restrict__ gptr,
                       float* __restrict__ dtw) {
  __shared__ __align__(16) float Cs[TT * TT];
  __shared__ float xna[TT];
  __shared__ float xnb[TT];

  const int pr = blockIdx.x;
  int a, b;
  tri_decode(pr, a, b);
  const int w = blockIdx.y;
  const float* x = w ? xt : xs;
  const float* xnw = xn + w * (BB * TT);
  const float* xa = x + (size_t)a * TT * DD;
  const float* xb = x + (size_t)b * TT * DD;
  const int tid = threadIdx.x;

  if (tid < TT) {
    xna[tid] = xnw[a * TT + tid];
    xnb[tid] = xnw[b * TT + tid];
  }
  constexpr int SROW = 36;
  float* xa_s = Cs;
  float* xb_s = Cs + TT * SROW;
  const int wv = tid >> 6;
  const int lane = tid & 63;
  const int tx = (lane & 7) + (wv & 1) * 8;
  const int ty = (lane >> 3) + (wv >> 1) * 8;
  const int t0 = ty * 6, s0 = tx * 6;
  float acc[6][6];
#pragma unroll
  for (int r = 0; r < 6; ++r)
#pragma unroll
    for (int c = 0; c < 6; ++c) acc[r][c] = 0.f;
  for (int d0 = 0; d0 < DD; d0 += 32) {
    __syncthreads();
    const float4* ga = reinterpret_cast<const float4*>(xa + d0);
    const float4* gb = reinterpret_cast<const float4*>(xb + d0);
    float4* sa = reinterpret_cast<float4*>(xa_s);
    float4* sb = reinterpret_cast<float4*>(xb_s);
#pragma unroll
    for (int it = 0; it < 3; ++it) {
      int idx = tid + it * 256;
      int t = idx >> 3, k4 = idx & 7;
      sa[t * (SROW / 4) + k4] = ga[t * (DD / 4) + k4];
      sb[t * (SROW / 4) + k4] = gb[t * (DD / 4) + k4];
    }
    __syncthreads();
#pragma unroll
    for (int k4 = 0; k4 < 8; ++k4) {
      float4 av4[6], bv4[6];
#pragma unroll
      for (int r = 0; r < 6; ++r)
        av4[r] = reinterpret_cast<const float4*>(xa_s + (t0 + r) * SROW)[k4];
#pragma unroll
      for (int c = 0; c < 6; ++c)
        bv4[c] = reinterpret_cast<const float4*>(xb_s + (s0 + c) * SROW)[k4];
#pragma unroll
      for (int r = 0; r < 6; ++r)
#pragma unroll
        for (int c = 0; c < 6; ++c) {
          acc[r][c] = fmaf(av4[r].x, bv4[c].x, acc[r][c]);
          acc[r][c] = fmaf(av4[r].y, bv4[c].y, acc[r][c]);
          acc[r][c] = fmaf(av4[r].z, bv4[c].z, acc[r][c]);
          acc[r][c] = fmaf(av4[r].w, bv4[c].w, acc[r][c]);
        }
    }
  }
  __syncthreads();
#pragma unroll
  for (int r = 0; r < 6; ++r) {
    float xr = xna[t0 + r];
#pragma unroll
    for (int c = 0; c < 6; ++c)
      Cs[(t0 + r) * TT + (s0 + c)] = xr + xnb[s0 + c] - 2.0f * acc[r][c];
  }
  __syncthreads();
  if (tid >= 64) return;

  const float gamma = gptr[0];
  const float rg = -1.0f / gamma;
  const int lm1 = (lane + 63) & 63;
  float A1 = FINF, B1 = FINF, A2 = FINF, B2 = FINF;
  for (int d = 0; d < 2 * TT - 1; ++d) {
    int jA = d - lane;
    bool vA = (jA >= 0) && (jA < TT);
    float cA = Cs[vA ? lane * TT + jA : 0];
    int iB = 64 + lane;
    int jB = d - iB;
    bool vB = (lane < 32) && (jB >= 0) && (jB < TT);
    float cB = Cs[vB ? iB * TT + jB : 0];
    float rA1 = __shfl(A1, lm1);
    float rB1 = __shfl(B1, lm1);
    float rA2 = __shfl(A2, lm1);
    float rB2 = __shfl(B2, lm1);
    const bool l0 = (lane == 0);
    float upA = l0 ? FINF : rA1;
    float dgA = l0 ? FINF : rA2;
    float upB = l0 ? rA1 : rB1;
    float dgB = l0 ? rA2 : rB2;
    float z0 = upA * rg, z1 = A1 * rg, z2 = dgA * rg;
    float m = fmaxf(fmaxf(z0, z1), z2);
    float s = expf(z0 - m) + expf(z1 - m) + expf(z2 - m);
    float sminA = -gamma * (m + logf(s));
    if (d == 0) sminA = 0.f;
    float y0 = upB * rg, y1 = B1 * rg, y2 = dgB * rg;
    float mb = fmaxf(fmaxf(y0, y1), y2);
    float sb2 = expf(y0 - mb) + expf(y1 - mb) + expf(y2 - mb);
    float sminB = -gamma * (mb + logf(sb2));
    float nA = vA ? cA + sminA : FINF;
    float nB = vB ? cB + sminB : FINF;
    A2 = A1; B2 = B1; A1 = nA; B1 = nB;
  }
  if (lane == 31) {
    float v = B1;
    dtw[w * NP + a * BB + b] = v;
    dtw[w * NP + b * BB + a] = v;
  }
}

// K3: means + normalized smooth-L1 (single block).
__global__ void reduce_kernel(const float* __restrict__ dtw,
                              float* __restrict__ out) {
  __shared__ double sh[256];
  const int tid = threadIdx.x;
  double ss = 0, st = 0;
  for (int k = tid; k < NP; k += 256) {
    ss += (double)dtw[k];
    st += (double)dtw[NP + k];
  }
  sh[tid] = ss; __syncthreads();
  for (int o = 128; o > 0; o >>= 1) { if (tid < o) sh[tid] += sh[tid + o]; __syncthreads(); }
  double sum_s = sh[0]; __syncthreads();
  sh[tid] = st; __syncthreads();
  for (int o = 128; o > 0; o >>= 1) { if (tid < o) sh[tid] += sh[tid + o]; __syncthreads(); }
  double sum_t = sh[0]; __syncthreads();

  float mean_s = (float)(sum_s / NP);
  float mean_t = (float)(sum_t / NP);

  double acc = 0;
  for (int k = tid; k < NP; k += 256) {
    float pred = dtw[k] / mean_s;
    float targ = dtw[NP + k] / mean_t;
    float d = pred - targ;
    float ad = fabsf(d);
    float v = ad < 1.f ? 0.5f * d * d : ad - 0.5f;
    acc += (double)v;
  }
  sh[tid] = acc; __syncthreads();
  for (int o = 128; o > 0; o >>= 1) { if (tid < o) sh[tid] += sh[tid + o]; __syncthreads(); }
  if (tid == 0) out[0] = (float)(sh[0] / NP);
}

extern "C" void kernel_launch(void* const* d_in, const int* in_sizes, int n_in,
                              void* d_out, int out_size, void* d_ws, size_t ws_size,
                              hipStream_t stream) {
  const float* student = (const float*)d_in[0];
  const float* teacher = (const float*)d_in[1];
  const float* gamma   = (const float*)d_in[2];
  float* ws = (float*)d_ws;

  const size_t cd_floats = (size_t)NPROB * CSZ;              // 9,732,096
  const size_t need = (cd_floats + 2 * NP + 2 * BB * TT) * sizeof(float);

  if (ws_size >= need) {
    float* Cd  = ws;
    float* dtw = ws + cd_floats;
    csq_kernel<<<dim3(NPAIR, 2), 256, 0, stream>>>(student, teacher, gamma, Cd);
    dp_kernel<<<NPROB, 64, 0, stream>>>(Cd, gamma, dtw);
    reduce_kernel<<<1, 256, 0, stream>>>(dtw, (float*)d_out);
  } else {
    float* dtw = ws;
    float* xnb = ws + 2 * NP;
    xn_kernel<<<24, 256, 0, stream>>>(student, teacher, xnb);
    sdtw_fused_kernel<<<dim3(NPAIR, 2), 256, 0, stream>>>(student, teacher, xnb, gamma, dtw);
    reduce_kernel<<<1, 256, 0, stream>>>(dtw, (float*)d_out);
  }
}